// Round 11
// baseline (151.433 us; speedup 1.0000x reference)
//
#include <hip/hip_runtime.h>

#define B_ 2
#define S_ 4096
#define D_ 768
#define H_ 12
#define DH_ 64
#define W_ 256
#define G_ 8
#define NEG_ (-1e9f)
#define NC_ 64
#define CK_ 64
#define WQB 128
#define NT_ 11
#define NWIN (B_ * H_ * (S_ / WQB))   // 768 win blocks

typedef __attribute__((ext_vector_type(4))) float f32x4;
typedef __attribute__((ext_vector_type(16))) float f32x16;
typedef __attribute__((ext_vector_type(8))) short s16x8;
typedef __attribute__((ext_vector_type(4))) short s16x4;
typedef unsigned short ushort_t;

__device__ __forceinline__ unsigned short f2bf(float f) {
    union { float f; unsigned u; } v; v.f = f;
    unsigned r = v.u + 0x7FFFu + ((v.u >> 16) & 1u);
    return (unsigned short)(r >> 16);
}
__device__ __forceinline__ float bf2f(unsigned short b) {
    union { unsigned u; float f; } v; v.u = ((unsigned)b) << 16;
    return v.f;
}
__device__ __forceinline__ unsigned cvtpk_bf16(float lo, float hi) {
    unsigned r;
    asm("v_cvt_pk_bf16_f32 %0, %1, %2" : "=v"(r) : "v"(lo), "v"(hi));
    return r;
}
__device__ __forceinline__ void gload16(const ushort_t* g, ushort_t* l) {
    __builtin_amdgcn_global_load_lds(
        (const __attribute__((address_space(1))) unsigned*)g,
        (__attribute__((address_space(3))) unsigned*)l, 16, 0, 0);
}
__device__ __forceinline__ float vmax16f(f32x16 v) {
    float a0 = fmaxf(v[0], v[1]), a1 = fmaxf(v[2], v[3]);
    float a2 = fmaxf(v[4], v[5]), a3 = fmaxf(v[6], v[7]);
    float a4 = fmaxf(v[8], v[9]), a5 = fmaxf(v[10], v[11]);
    float a6 = fmaxf(v[12], v[13]), a7 = fmaxf(v[14], v[15]);
    return fmaxf(fmaxf(fmaxf(a0, a1), fmaxf(a2, a3)),
                 fmaxf(fmaxf(a4, a5), fmaxf(a6, a7)));
}
__device__ __forceinline__ float vsum16f(f32x16 v) {
    float a0 = v[0] + v[1], a1 = v[2] + v[3];
    float a2 = v[4] + v[5], a3 = v[6] + v[7];
    float a4 = v[8] + v[9], a5 = v[10] + v[11];
    float a6 = v[12] + v[13], a7 = v[14] + v[15];
    return ((a0 + a1) + (a2 + a3)) + ((a4 + a5) + (a6 + a7));
}

// ---------------------------------------------------------------------------
// Fused prologue: hs->bf16 (blocks 0..3071), weight transpose+convert
// (blocks 3072..5951), qg GEMM (blocks 5952..5999).
// ---------------------------------------------------------------------------
__global__ __launch_bounds__(256) void fused_pre(const float* __restrict__ hs,
                                                 const float* __restrict__ W0,
                                                 const float* __restrict__ W1,
                                                 const float* __restrict__ W2,
                                                 const float* __restrict__ W3,
                                                 const float* __restrict__ W4,
                                                 const float* __restrict__ Wqg,
                                                 ushort_t* __restrict__ hs_bf,
                                                 ushort_t* __restrict__ wt,
                                                 float* __restrict__ qg) {
    __shared__ float smf[2 * D_];
    const int bid = blockIdx.x;
    const int t = threadIdx.x;

    if (bid < 3072) {
        const int i = bid * 256 + t;
        float4 a = *(const float4*)&hs[(size_t)i * 8];
        float4 c = *(const float4*)&hs[(size_t)i * 8 + 4];
        s16x8 o;
        o[0] = (short)f2bf(a.x); o[1] = (short)f2bf(a.y);
        o[2] = (short)f2bf(a.z); o[3] = (short)f2bf(a.w);
        o[4] = (short)f2bf(c.x); o[5] = (short)f2bf(c.y);
        o[6] = (short)f2bf(c.z); o[7] = (short)f2bf(c.w);
        *(s16x8*)&hs_bf[(size_t)i * 8] = o;
    } else if (bid < 5952) {
        const int bid2 = bid - 3072;
        const int w = bid2 / 576;
        const int rem = bid2 - w * 576;
        const int k0 = (rem / 24) * 32;
        const int n0 = (rem % 24) * 32;
        const float* Wsrc = (w == 0) ? W0 : (w == 1) ? W1 : (w == 2) ? W2 : (w == 3) ? W3 : W4;
        const float scl = (w == 0) ? 0.125f * 1.44269504f : 1.0f;   // Wq in exp2 domain
        const int r = t >> 3, c4 = (t & 7) * 4;
        float4 src = *(const float4*)&Wsrc[(size_t)(k0 + r) * D_ + n0 + c4];
        smf[r * 33 + c4 + 0] = src.x; smf[r * 33 + c4 + 1] = src.y;
        smf[r * 33 + c4 + 2] = src.z; smf[r * 33 + c4 + 3] = src.w;
        __syncthreads();
        s16x4 o;
        o[0] = (short)f2bf(smf[(c4 + 0) * 33 + r] * scl);
        o[1] = (short)f2bf(smf[(c4 + 1) * 33 + r] * scl);
        o[2] = (short)f2bf(smf[(c4 + 2) * 33 + r] * scl);
        o[3] = (short)f2bf(smf[(c4 + 3) * 33 + r] * scl);
        *(s16x4*)&wt[((size_t)(w * D_ + n0 + r)) * D_ + k0 + c4] = o;
    } else {
        const int bid3 = bid - 5952;
        const int rp = bid3 / 6;
        const int c0 = (bid3 - rp * 6) * 128;
        const int r = t >> 7, cl = t & 127;
        for (int i = t; i < 2 * D_; i += 256) {
            const int rr = i / D_, kk = i - rr * D_;
            const int row = rp * 2 + rr;
            const int b = row >> 3, g = row & 7;
            smf[rr * D_ + kk] = hs[((size_t)b * S_ + g) * D_ + kk];
        }
        __syncthreads();
        float a0 = 0.f, a1 = 0.f, a2 = 0.f, a3 = 0.f;
        const float* wp = &Wqg[c0 + cl];
        for (int kk = 0; kk < D_; kk += 4) {
            a0 += smf[r * D_ + kk + 0] * wp[(size_t)(kk + 0) * D_];
            a1 += smf[r * D_ + kk + 1] * wp[(size_t)(kk + 1) * D_];
            a2 += smf[r * D_ + kk + 2] * wp[(size_t)(kk + 2) * D_];
            a3 += smf[r * D_ + kk + 3] * wp[(size_t)(kk + 3) * D_];
        }
        const int row = rp * 2 + r;
        qg[(size_t)row * D_ + c0 + cl] = (a0 + a1 + a2 + a3) * 0.125f;
    }
}

// ---------------------------------------------------------------------------
// Fused projection GEMM, m97-style (known-good 745 TF).
// ---------------------------------------------------------------------------
__global__ __launch_bounds__(256, 2) void proj_mfma(const ushort_t* __restrict__ A,
                                                    const ushort_t* __restrict__ Bt,
                                                    ushort_t* __restrict__ oq,
                                                    ushort_t* __restrict__ ok,
                                                    ushort_t* __restrict__ ov,
                                                    ushort_t* __restrict__ okg,
                                                    ushort_t* __restrict__ ovg) {
    __shared__ char smem[34048];
    ushort_t* Al = (ushort_t*)smem;
    ushort_t* Bl = Al + 128 * 64;

    const int t = threadIdx.x;
    const int m0 = blockIdx.x * 128;
    const int n0 = blockIdx.y * 128;
    const int lane = t & 63;
    const int w = t >> 6;
    const int wm = (w >> 1) * 64, wn = (w & 1) * 64;
    const int ln = lane & 15, hi = lane >> 4;

    const int srow_in_call = lane >> 3;
    const int scol = ((lane & 7) ^ srow_in_call) * 8;

    f32x4 acc[4][4];
#pragma unroll
    for (int mi = 0; mi < 4; ++mi)
#pragma unroll
        for (int ni = 0; ni < 4; ++ni) acc[mi][ni] = (f32x4){0.f, 0.f, 0.f, 0.f};

    for (int k0 = 0; k0 < D_; k0 += 64) {
        __syncthreads();
#pragma unroll
        for (int j = 0; j < 4; ++j) {
            const int rbase = (w * 4 + j) * 8;
            const int row = rbase + srow_in_call;
            gload16(&A[(size_t)(m0 + row) * D_ + k0 + scol], &Al[rbase * 64]);
            gload16(&Bt[(size_t)(n0 + row) * D_ + k0 + scol], &Bl[rbase * 64]);
        }
        __syncthreads();

#pragma unroll
        for (int ks = 0; ks < 2; ++ks) {
            s16x8 af[4], bf[4];
#pragma unroll
            for (int i = 0; i < 4; ++i) {
                const int ar = wm + i * 16 + ln;
                const int br = wn + i * 16 + ln;
                const int slot = (4 * ks + hi) ^ (ln & 7);
                af[i] = *(const s16x8*)&Al[ar * 64 + slot * 8];
                bf[i] = *(const s16x8*)&Bl[br * 64 + slot * 8];
            }
#pragma unroll
            for (int mi = 0; mi < 4; ++mi)
#pragma unroll
                for (int ni = 0; ni < 4; ++ni)
                    acc[mi][ni] = __builtin_amdgcn_mfma_f32_16x16x32_bf16(af[mi], bf[ni], acc[mi][ni], 0, 0, 0);
        }
    }

    float* scr = (float*)smem;
    const int rl = t >> 2, cs = (t & 3) * 32;
    const int ng = n0 + cs;
    const int w_idx = ng / D_;
    const int cb = ng - w_idx * D_;
    const int hh = cb >> 6, dd = cb & 63;
    ushort_t* dst = (w_idx == 0) ? oq : (w_idx == 1) ? ok : (w_idx == 2) ? ov
                    : (w_idx == 3) ? okg : ovg;

#pragma unroll
    for (int r = 0; r < 2; ++r) {
        __syncthreads();
        if ((w >> 1) == r) {
#pragma unroll
            for (int mi = 0; mi < 4; ++mi)
#pragma unroll
                for (int ni = 0; ni < 4; ++ni)
#pragma unroll
                    for (int rr = 0; rr < 4; ++rr)
                        scr[(mi * 16 + hi * 4 + rr) * 132 + wn + ni * 16 + ln] = acc[mi][ni][rr];
        }
        __syncthreads();
        const int m = m0 + r * 64 + rl;
        const int bb = m >> 12, s = m & 4095;
        ushort_t* drow = dst + ((size_t)(bb * H_ + hh) * S_ + s) * DH_ + dd;
        const float* srcp = scr + rl * 132 + cs;
#pragma unroll
        for (int seg = 0; seg < 4; ++seg) {
            float4 lo = *(const float4*)&srcp[seg * 8];
            float4 hi4 = *(const float4*)&srcp[seg * 8 + 4];
            s16x8 o;
            o[0] = (short)f2bf(lo.x); o[1] = (short)f2bf(lo.y);
            o[2] = (short)f2bf(lo.z); o[3] = (short)f2bf(lo.w);
            o[4] = (short)f2bf(hi4.x); o[5] = (short)f2bf(hi4.y);
            o[6] = (short)f2bf(hi4.z); o[7] = (short)f2bf(hi4.w);
            *(s16x8*)&drow[seg * 8] = o;
        }
    }
}

// ---------------------------------------------------------------------------
// Merged kernel: blocks 0..NWIN-1 = windowed attention; blocks NWIN.. =
// global-attention split-K partials.  This round: (1) all tile masks
// precomputed once into Mv[20]; (2) T14 async reg-staging (prefetch tile
// t+1's K/V during tile t's compute).
// ---------------------------------------------------------------------------
__global__ __launch_bounds__(256, 2) void win_glob(const ushort_t* __restrict__ q,
                                                   const ushort_t* __restrict__ k,
                                                   const ushort_t* __restrict__ v,
                                                   const float* __restrict__ am,
                                                   float* __restrict__ out,
                                                   const float* __restrict__ qg,
                                                   const ushort_t* __restrict__ kg,
                                                   const ushort_t* __restrict__ vg,
                                                   float* __restrict__ pout,
                                                   float* __restrict__ pm,
                                                   float* __restrict__ pl) {
    __shared__ char smem[39424];
    const int bid = blockIdx.x;
    const int t = threadIdx.x;

    if (bid >= NWIN) {
        // ================= global attention partials =================
        const int idx = bid - NWIN;
        const int c = idx & 63;
        const int hb = idx >> 6;
        const int h = hb % H_;
        const int b = hb / H_;
        const int bh = b * H_ + h;
        const size_t base = (size_t)bh * S_ * DH_;
        const int jg0 = c * CK_;

        float* qs = (float*)smem;                 // [8][64]
        float* kt = qs + G_ * DH_;                // [64][69]
        float* vt = kt + CK_ * 69;                // [64][68]
        float* ps = vt + CK_ * 68;                // [8][64]

        for (int i = t; i < G_ * DH_; i += 256)
            qs[(i >> 6) * DH_ + (i & 63)] = qg[(size_t)(b * G_ + (i >> 6)) * D_ + h * DH_ + (i & 63)];
        {
            const int row = t >> 2, off = (t & 3) * 16;
            const ushort_t* kr = &kg[base + (size_t)(jg0 + row) * DH_ + off];
            const ushort_t* vr = &vg[base + (size_t)(jg0 + row) * DH_ + off];
            s16x8 ka = *(const s16x8*)kr;
            s16x8 kb2 = *(const s16x8*)(kr + 8);
            s16x8 va = *(const s16x8*)vr;
            s16x8 vb = *(const s16x8*)(vr + 8);
#pragma unroll
            for (int i = 0; i < 8; ++i) {
                kt[row * 69 + off + i] = bf2f((ushort_t)ka[i]);
                kt[row * 69 + off + 8 + i] = bf2f((ushort_t)kb2[i]);
                vt[row * 68 + off + i] = bf2f((ushort_t)va[i]);
                vt[row * 68 + off + 8 + i] = bf2f((ushort_t)vb[i]);
            }
        }
        __syncthreads();

        const int g = t >> 5, jl = t & 31;
        float sc0 = 0.f, sc1 = 0.f;
#pragma unroll 8
        for (int d = 0; d < DH_; ++d) {
            const float qv = qs[g * DH_ + d];
            sc0 += qv * kt[jl * 69 + d];
            sc1 += qv * kt[(jl + 32) * 69 + d];
        }
        if (!(am[(size_t)b * S_ + jg0 + jl] > 0.5f)) sc0 = NEG_;
        if (!(am[(size_t)b * S_ + jg0 + jl + 32] > 0.5f)) sc1 = NEG_;

        float mm = fmaxf(sc0, sc1);
        mm = fmaxf(mm, __shfl_xor(mm, 1));
        mm = fmaxf(mm, __shfl_xor(mm, 2));
        mm = fmaxf(mm, __shfl_xor(mm, 4));
        mm = fmaxf(mm, __shfl_xor(mm, 8));
        mm = fmaxf(mm, __shfl_xor(mm, 16));
        const float p0 = __expf(sc0 - mm);
        const float p1 = __expf(sc1 - mm);
        float ls = p0 + p1;
        ls += __shfl_xor(ls, 1);
        ls += __shfl_xor(ls, 2);
        ls += __shfl_xor(ls, 4);
        ls += __shfl_xor(ls, 8);
        ls += __shfl_xor(ls, 16);
        ps[g * CK_ + jl] = p0;
        ps[g * CK_ + jl + 32] = p1;
        if (jl == 0) {
            pm[((size_t)bh * NC_ + c) * G_ + g] = mm;
            pl[((size_t)bh * NC_ + c) * G_ + g] = ls;
        }
        __syncthreads();

#pragma unroll
        for (int pass = 0; pass < 2; ++pass) {
            const int gg = (t >> 6) + pass * 4;
            const int d = t & 63;
            float acc = 0.f;
#pragma unroll 8
            for (int j = 0; j < CK_; ++j) acc += ps[gg * CK_ + j] * vt[j * 68 + d];
            pout[(((size_t)bh * NC_ + c) * G_ + gg) * DH_ + d] = acc;
        }
        return;
    }

    // ================= windowed attention =================
    ushort_t* Kl = (ushort_t*)smem;            // [64][72]
    ushort_t* Vt = Kl + 64 * 72;               // [64 d][66 keys]
    unsigned* Mv = (unsigned*)(Vt + 64 * 66);  // [2 * (NT_-1)] precomputed masks
    float* Ow = (float*)smem;                  // epilogue: [4 waves][32][68]

    // XCD-chunked swizzle: 768 blocks, 96 per XCD, n fastest within chunk.
    const int wg = (bid & 7) * 96 + (bid >> 3);
    const int n = wg & 31;
    const int h = (wg >> 5) % H_;
    const int b = wg / (32 * H_);

    const int lane = t & 63, w = t >> 6;
    const int l31 = lane & 31, h5 = lane >> 5;
    const int q0w = n * WQB + w * 32;
    const int q_abs = q0w + l31;
    const size_t bh = (size_t)(b * H_ + h) * S_;

    s16x8 qf[4];
#pragma unroll
    for (int ks = 0; ks < 4; ++ks)
        qf[ks] = *(const s16x8*)&q[(bh + q_abs) * DH_ + ks * 16 + 8 * h5];

    f32x16 oacc[2];
#pragma unroll
    for (int dt = 0; dt < 2; ++dt)
#pragma unroll
        for (int i = 0; i < 16; ++i) oacc[dt][i] = 0.f;
    float m_run, l_run;

    const int srow = t >> 2, soff = (t & 3) * 16;

    // ---- stage tile 0 (global keys) + precompute ALL window-tile masks ----
    {
        const ushort_t* krow = &k[(bh + srow) * DH_ + soff];
        s16x8 k0v = *(const s16x8*)krow;
        s16x8 k1v = *(const s16x8*)(krow + 8);
        *(s16x8*)&Kl[srow * 72 + soff] = k0v;
        *(s16x8*)&Kl[srow * 72 + soff + 8] = k1v;
        const ushort_t* vrow = &v[(bh + srow) * DH_ + soff];
        s16x8 v0v = *(const s16x8*)vrow;
        s16x8 v1v = *(const s16x8*)(vrow + 8);
#pragma unroll
        for (int i = 0; i < 8; ++i) {
            Vt[(soff + i) * 66 + srow] = (ushort_t)v0v[i];
            Vt[(soff + 8 + i) * 66 + srow] = (ushort_t)v1v[i];
        }
    }
    if (w == 0) {
#pragma unroll
        for (int tt = 1; tt < NT_; ++tt) {
            const int p2 = n * WQB - W_ + (tt - 1) * 64 + lane;
            const bool ok = (p2 >= G_) && (p2 < S_) &&
                            (am[(size_t)b * S_ + (p2 < 0 ? 0 : (p2 >= S_ ? S_ - 1 : p2))] > 0.5f);
            unsigned long long bal = __ballot(ok);
            if (lane == 0) {
                Mv[2 * (tt - 1)] = (unsigned)bal;
                Mv[2 * (tt - 1) + 1] = (unsigned)(bal >> 32);
            }
        }
    }
    __syncthreads();

    // ---- prefetch tile 1 K/V into registers (flies during tile-0 compute) --
    s16x8 kr0, kr1, vr0, vr1;
    {
        const int p = n * WQB - W_ + srow;
        const int pr = p < 0 ? 0 : p;
        const ushort_t* krow = &k[(bh + pr) * DH_ + soff];
        kr0 = *(const s16x8*)krow;
        kr1 = *(const s16x8*)(krow + 8);
        const ushort_t* vrow = &v[(bh + pr) * DH_ + soff];
        vr0 = *(const s16x8*)vrow;
        vr1 = *(const s16x8*)(vrow + 8);
    }

    // ---- compute tile 0 (specialized: keys 0..7 -> regs 0-3 of st=0) ----
    {
        f32x16 s0;
#pragma unroll
        for (int i = 0; i < 16; ++i) s0[i] = 0.f;
#pragma unroll
        for (int ks = 0; ks < 4; ++ks) {
            s16x8 kf = *(const s16x8*)&Kl[l31 * 72 + ks * 16 + 8 * h5];
            s0 = __builtin_amdgcn_mfma_f32_32x32x16_bf16(kf, qf[ks], s0, 0, 0, 0);
        }
        float tmax = fmaxf(fmaxf(s0[0], s0[1]), fmaxf(s0[2], s0[3]));
        tmax = fmaxf(tmax, __shfl_xor(tmax, 32));
        m_run = tmax;
        float p0 = exp2f(s0[0] - m_run), p1 = exp2f(s0[1] - m_run);
        float p2 = exp2f(s0[2] - m_run), p3 = exp2f(s0[3] - m_run);
        float psum = (p0 + p1) + (p2 + p3);
        psum += __shfl_xor(psum, 32);
        l_run = psum;
        const unsigned Au = cvtpk_bf16(p0, p1);
        const unsigned Bu = cvtpk_bf16(p2, p3);
        const unsigned send0 = h5 ? Au : 0u;
        const unsigned send1 = h5 ? Bu : 0u;
        const unsigned recv0 = __shfl_xor((int)send0, 32);
        const unsigned recv1 = __shfl_xor((int)send1, 32);
        union { unsigned u[4]; s16x8 v8; } pu;
        pu.u[0] = h5 ? recv0 : Au;
        pu.u[1] = h5 ? recv1 : Bu;
        pu.u[2] = h5 ? 0u : recv0;
        pu.u[3] = h5 ? 0u : recv1;
#pragma unroll
        for (int dt = 0; dt < 2; ++dt) {
            const int vbase = (dt * 32 + l31) * 66 + 8 * h5;
            union { unsigned u[4]; s16x8 v8; } vf;
            vf.u[0] = *(const unsigned*)&Vt[vbase + 0];
            vf.u[1] = *(const unsigned*)&Vt[vbase + 2];
            vf.u[2] = *(const unsigned*)&Vt[vbase + 4];
            vf.u[3] = *(const unsigned*)&Vt[vbase + 6];
            oacc[dt] = __builtin_amdgcn_mfma_f32_32x32x16_bf16(vf.v8, pu.v8, oacc[dt], 0, 0, 0);
        }
    }

    // ---- window tiles (async reg-staged) ----
    for (int tt = 1; tt < NT_; ++tt) {
        const int pbase = n * WQB - W_ + (tt - 1) * 64;
        __syncthreads();
        // write tile tt's prefetched regs -> LDS
        *(s16x8*)&Kl[srow * 72 + soff] = kr0;
        *(s16x8*)&Kl[srow * 72 + soff + 8] = kr1;
#pragma unroll
        for (int i = 0; i < 8; ++i) {
            Vt[(soff + i) * 66 + srow] = (ushort_t)vr0[i];
            Vt[(soff + 8 + i) * 66 + srow] = (ushort_t)vr1[i];
        }
        __syncthreads();

        // issue tile tt+1's loads (hidden under this tile's compute)
        if (tt < NT_ - 1) {
            const int p = pbase + 64 + srow;
            const int pr = p < 0 ? 0 : (p >= S_ ? S_ - 1 : p);
            const ushort_t* krow = &k[(bh + pr) * DH_ + soff];
            kr0 = *(const s16x8*)krow;
            kr1 = *(const s16x8*)(krow + 8);
            const ushort_t* vrow = &v[(bh + pr) * DH_ + soff];
            vr0 = *(const s16x8*)vrow;
            vr1 = *(const s16x8*)(vrow + 8);
        }

        // wave-level band skip
        if (pbase > q0w + 31 + W_ || pbase + 63 < q0w - W_) continue;

        // ---- QK^T (swapped) ----
        f32x16 sc[2];
#pragma unroll
        for (int st = 0; st < 2; ++st)
#pragma unroll
            for (int i = 0; i < 16; ++i) sc[st][i] = 0.f;
#pragma unroll
        for (int st = 0; st < 2; ++st)
#pragma unroll
            for (int ks = 0; ks < 4; ++ks) {
                s16x8 kf = *(const s16x8*)&Kl[(st * 32 + l31) * 72 + ks * 16 + 8 * h5];
                sc[st] = __builtin_amdgcn_mfma_f32_32x32x16_bf16(kf, qf[ks], sc[st], 0, 0, 0);
            }

        // ---- mask (fast-path for interior tiles) + tree max ----
        const unsigned mv0 = Mv[2 * (tt - 1)], mv1 = Mv[2 * (tt - 1) + 1];
        const bool fullt = ((mv0 & mv1) == 0xFFFFFFFFu) &&
                           (pbase >= q0w + 31 - W_) && (pbase + 63 <= q0w + W_);
        if (!fullt) {
#pragma unroll
            for (int st = 0; st < 2; ++st)
#pragma unroll
                for (int reg = 0; reg < 16; ++reg) {
                    const int cst = (reg & 3) + 8 * (reg >> 2);
                    const int crow = cst + 4 * h5;
                    const int key_abs = pbase + st * 32 + crow;
                    const unsigned mvx = (st == 0) ? mv0 : mv1;
                    const bool valid = ((mvx >> crow) & 1u) &&
                                       (key_abs >= q_abs - W_) && (key_abs <= q_abs + W_);
                    sc[st][reg] = valid ? sc[st][reg] : -1e30f;
                }
        }
        float tmax = fmaxf(vmax16f(sc[0]), vmax16f(sc[1]));
        tmax = fmaxf(tmax, __shfl_xor(tmax, 32));

        // ---- defer-max online softmax (exp2 domain) ----
        if (__any(tmax > m_run + 11.5f)) {
            const float mnew = fmaxf(m_run, tmax);
            const float f = exp2f(m_run - mnew);
            l_run *= f;
#pragma unroll
            for (int dt = 0; dt < 2; ++dt)
#pragma unroll
                for (int i = 0; i < 16; ++i) oacc[dt][i] *= f;
            m_run = mnew;
        }
#pragma unroll
        for (int st = 0; st < 2; ++st)
#pragma unroll
            for (int reg = 0; reg < 16; ++reg)
                sc[st][reg] = exp2f(sc[st][reg] - m_run);
        float psum = vsum16f(sc[0]) + vsum16f(sc[1]);
        psum += __shfl_xor(psum, 32);
        l_run += psum;

        // ---- P -> bf16 B-fragments + PV ----
#pragma unroll
        for (int ks = 0; ks < 4; ++ks) {
            const int st = ks >> 1, k8 = (ks & 1) * 8;
            const unsigned Au = cvtpk_bf16(sc[st][k8 + 0], sc[st][k8 + 1]);
            const unsigned Bu = cvtpk_bf16(sc[st][k8 + 2], sc[st][k8 + 3]);
            const unsigned Cu = cvtpk_bf16(sc[st][k8 + 4], sc[st][k8 + 5]);
            const unsigned Du = cvtpk_bf16(sc[st][k8 + 6], sc[st][k8 + 7]);
            const unsigned send0 = h5 ? Au : Cu;
            const unsigned send1 = h5 ? Bu : Du;
            const unsigned recv0 = __shfl_xor((int)send0, 32);
            const unsigned recv1 = __shfl_xor((int)send1, 32);
            union { unsigned u[4]; s16x8 v8; } pu;
            pu.u[0] = h5 ? recv0 : Au;
            pu.u[1] = h5 ? recv1 : Bu;
            pu.u[2] = h5 ? Cu : recv0;
            pu.u[3] = h5 ? Du : recv1;
#pragma unroll
            for (int dt = 0; dt < 2; ++dt) {
                const int vbase = (dt * 32 + l31) * 66 + ks * 16 + 8 * h5;
                union { unsigned u[4]; s16x8 v8; } vf;
                vf.u[0] = *(const unsigned*)&Vt[vbase + 0];
                vf.u[1] = *(const unsigned*)&Vt[vbase + 2];
                vf.u[2] = *(const unsigned*)&Vt[vbase + 4];
                vf.u[3] = *(const unsigned*)&Vt[vbase + 6];
                oacc[dt] = __builtin_amdgcn_mfma_f32_32x32x16_bf16(vf.v8, pu.v8, oacc[dt], 0, 0, 0);
            }
        }
    }

    // ---- epilogue: O^T -> O via LDS, coalesced store ----
    __syncthreads();
    const float inv = 1.0f / l_run;
    float* OwW = Ow + w * 32 * 68;
#pragma unroll
    for (int dt = 0; dt < 2; ++dt)
#pragma unroll
        for (int reg = 0; reg < 16; ++reg) {
            const int d = dt * 32 + (reg & 3) + 8 * (reg >> 2) + 4 * h5;
            OwW[l31 * 68 + d] = oacc[dt][reg] * inv;
        }
    asm volatile("s_waitcnt lgkmcnt(0)" ::: "memory");
    const int qq = lane >> 1, half = lane & 1;
    const float* src = &OwW[qq * 68 + half * 32];
    float* dstp = &out[((size_t)b * S_ + q0w + qq) * D_ + h * DH_ + half * 32];
#pragma unroll
    for (int j = 0; j < 8; ++j)
        *(float4*)&dstp[j * 4] = *(const float4*)&src[j * 4];
}

// ---------------------------------------------------------------------------
// Global attention phase B: combine chunks (overwrites first-G rows, last).
// ---------------------------------------------------------------------------
__global__ __launch_bounds__(256) void glob_reduce(const float* __restrict__ pout,
                                                   const float* __restrict__ pm,
                                                   const float* __restrict__ pl,
                                                   float* __restrict__ out) {
    const int bh = blockIdx.x;
    const int b = bh / H_, h = bh - b * H_;
    const int t = threadIdx.x;

    __shared__ float wc[G_][NC_];
    __shared__ float wsum[G_];

    const int g = t >> 5, cl = t & 31;
    const float m0 = pm[((size_t)bh * NC_ + cl) * G_ + g];
    const float m1 = pm[((size_t)bh * NC_ + cl + 32) * G_ + g];
    float M = fmaxf(m0, m1);
    M = fmaxf(M, __shfl_xor(M, 1));
    M = fmaxf(M, __shfl_xor(M, 2));
    M = fmaxf(M, __shfl_xor(M, 4));
    M = fmaxf(M, __shfl_xor(M, 8));
    M = fmaxf(M, __shfl_xor(M, 16));
    const float w0 = __expf(m0 - M);
    const float w1 = __expf(m1 - M);
    float S = w0 * pl[((size_t)bh * NC_ + cl) * G_ + g] +
              w1 * pl[((size_t)bh * NC_ + cl + 32) * G_ + g];
    S += __shfl_xor(S, 1);
    S += __shfl_xor(S, 2);
    S += __shfl_xor(S, 4);
    S += __shfl_xor(S, 8);
    S += __shfl_xor(S, 16);
    wc[g][cl] = w0;
    wc[g][cl + 32] = w1;
    if (cl == 0) wsum[g] = S;
    __syncthreads();

#pragma unroll
    for (int pass = 0; pass < 2; ++pass) {
        const int gg = (t >> 6) + pass * 4;
        const int d = t & 63;
        float acc = 0.f;
        for (int c2 = 0; c2 < NC_; ++c2)
            acc += wc[gg][c2] * pout[(((size_t)bh * NC_ + c2) * G_ + gg) * DH_ + d];
        out[((size_t)b * S_ + gg) * D_ + h * DH_ + d] = acc / wsum[gg];
    }
}

// ---------------------------------------------------------------------------
extern "C" void kernel_launch(void* const* d_in, const int* in_sizes, int n_in,
                              void* d_out, int out_size, void* d_ws, size_t ws_size,
                              hipStream_t stream) {
    (void)in_sizes; (void)n_in; (void)out_size; (void)ws_size;

    const float* hs    = (const float*)d_in[0];
    const float* amask = (const float*)d_in[1];
    const float* Wq    = (const float*)d_in[2];
    const float* Wk    = (const float*)d_in[3];
    const float* Wv    = (const float*)d_in[4];
    const float* Wqg   = (const float*)d_in[5];
    const float* Wkg   = (const float*)d_in[6];
    const float* Wvg   = (const float*)d_in[7];
    float* out = (float*)d_out;

    char* p = (char*)d_ws;
    ushort_t* hs_bf = (ushort_t*)p; p += (size_t)B_ * S_ * D_ * 2;
    ushort_t* wt    = (ushort_t*)p; p += (size_t)5 * D_ * D_ * 2;
    const size_t per = (size_t)B_ * H_ * S_ * DH_;
    ushort_t* qb  = (ushort_t*)p; p += per * 2;
    ushort_t* kb  = (ushort_t*)p; p += per * 2;
    ushort_t* vb  = (ushort_t*)p; p += per * 2;
    ushort_t* kgb = (ushort_t*)p; p += per * 2;
    ushort_t* vgb = (ushort_t*)p; p += per * 2;
    float* qg   = (float*)p; p += (size_t)B_ * G_ * D_ * 4;
    float* pout = (float*)p; p += (size_t)B_ * H_ * NC_ * G_ * DH_ * 4;
    float* pm   = (float*)p; p += (size_t)B_ * H_ * NC_ * G_ * 4;
    float* pl   = (float*)p;

    fused_pre<<<6000, 256, 0, stream>>>(hs, Wq, Wk, Wv, Wkg, Wvg, Wqg, hs_bf, wt, qg);
    proj_mfma<<<dim3(B_ * S_ / 128, 5 * D_ / 128), 256, 0, stream>>>(hs_bf, wt, qb, kb, vb, kgb, vgb);
    win_glob<<<NWIN + NC_ * H_ * B_, 256, 0, stream>>>(qb, kb, vb, amask, out,
                                                       qg, kgb, vgb, pout, pm, pl);
    glob_reduce<<<B_ * H_, 256, 0, stream>>>(pout, pm, pl, out);
}

// Round 12
// 141.949 us; speedup vs baseline: 1.0668x; 1.0668x over previous
//
#include <hip/hip_runtime.h>

#define B_ 2
#define S_ 4096
#define D_ 768
#define H_ 12
#define DH_ 64
#define W_ 256
#define G_ 8
#define NEG_ (-1e9f)
#define NC_ 64
#define CK_ 64
#define WQB 128
#define NT_ 11
#define NWIN (B_ * H_ * (S_ / WQB))   // 768 win blocks

typedef __attribute__((ext_vector_type(4))) float f32x4;
typedef __attribute__((ext_vector_type(16))) float f32x16;
typedef __attribute__((ext_vector_type(8))) short s16x8;
typedef __attribute__((ext_vector_type(4))) short s16x4;
typedef unsigned short ushort_t;

__device__ __forceinline__ unsigned short f2bf(float f) {
    union { float f; unsigned u; } v; v.f = f;
    unsigned r = v.u + 0x7FFFu + ((v.u >> 16) & 1u);
    return (unsigned short)(r >> 16);
}
__device__ __forceinline__ float bf2f(unsigned short b) {
    union { unsigned u; float f; } v; v.u = ((unsigned)b) << 16;
    return v.f;
}
__device__ __forceinline__ unsigned cvtpk_bf16(float lo, float hi) {
    unsigned r;
    asm("v_cvt_pk_bf16_f32 %0, %1, %2" : "=v"(r) : "v"(lo), "v"(hi));
    return r;
}
__device__ __forceinline__ void gload16(const ushort_t* g, ushort_t* l) {
    __builtin_amdgcn_global_load_lds(
        (const __attribute__((address_space(1))) unsigned*)g,
        (__attribute__((address_space(3))) unsigned*)l, 16, 0, 0);
}
__device__ __forceinline__ float vmax16f(f32x16 v) {
    float a0 = fmaxf(v[0], v[1]), a1 = fmaxf(v[2], v[3]);
    float a2 = fmaxf(v[4], v[5]), a3 = fmaxf(v[6], v[7]);
    float a4 = fmaxf(v[8], v[9]), a5 = fmaxf(v[10], v[11]);
    float a6 = fmaxf(v[12], v[13]), a7 = fmaxf(v[14], v[15]);
    return fmaxf(fmaxf(fmaxf(a0, a1), fmaxf(a2, a3)),
                 fmaxf(fmaxf(a4, a5), fmaxf(a6, a7)));
}
__device__ __forceinline__ float vsum16f(f32x16 v) {
    float a0 = v[0] + v[1], a1 = v[2] + v[3];
    float a2 = v[4] + v[5], a3 = v[6] + v[7];
    float a4 = v[8] + v[9], a5 = v[10] + v[11];
    float a6 = v[12] + v[13], a7 = v[14] + v[15];
    return ((a0 + a1) + (a2 + a3)) + ((a4 + a5) + (a6 + a7));
}

// ---------------------------------------------------------------------------
// Fused prologue: hs->bf16 (blocks 0..3071), weight transpose+convert
// (blocks 3072..5951), qg GEMM (blocks 5952..5999).
// ---------------------------------------------------------------------------
__global__ __launch_bounds__(256) void fused_pre(const float* __restrict__ hs,
                                                 const float* __restrict__ W0,
                                                 const float* __restrict__ W1,
                                                 const float* __restrict__ W2,
                                                 const float* __restrict__ W3,
                                                 const float* __restrict__ W4,
                                                 const float* __restrict__ Wqg,
                                                 ushort_t* __restrict__ hs_bf,
                                                 ushort_t* __restrict__ wt,
                                                 float* __restrict__ qg) {
    __shared__ float smf[2 * D_];
    const int bid = blockIdx.x;
    const int t = threadIdx.x;

    if (bid < 3072) {
        const int i = bid * 256 + t;
        float4 a = *(const float4*)&hs[(size_t)i * 8];
        float4 c = *(const float4*)&hs[(size_t)i * 8 + 4];
        s16x8 o;
        o[0] = (short)f2bf(a.x); o[1] = (short)f2bf(a.y);
        o[2] = (short)f2bf(a.z); o[3] = (short)f2bf(a.w);
        o[4] = (short)f2bf(c.x); o[5] = (short)f2bf(c.y);
        o[6] = (short)f2bf(c.z); o[7] = (short)f2bf(c.w);
        *(s16x8*)&hs_bf[(size_t)i * 8] = o;
    } else if (bid < 5952) {
        const int bid2 = bid - 3072;
        const int w = bid2 / 576;
        const int rem = bid2 - w * 576;
        const int k0 = (rem / 24) * 32;
        const int n0 = (rem % 24) * 32;
        const float* Wsrc = (w == 0) ? W0 : (w == 1) ? W1 : (w == 2) ? W2 : (w == 3) ? W3 : W4;
        const float scl = (w == 0) ? 0.125f * 1.44269504f : 1.0f;   // Wq in exp2 domain
        const int r = t >> 3, c4 = (t & 7) * 4;
        float4 src = *(const float4*)&Wsrc[(size_t)(k0 + r) * D_ + n0 + c4];
        smf[r * 33 + c4 + 0] = src.x; smf[r * 33 + c4 + 1] = src.y;
        smf[r * 33 + c4 + 2] = src.z; smf[r * 33 + c4 + 3] = src.w;
        __syncthreads();
        s16x4 o;
        o[0] = (short)f2bf(smf[(c4 + 0) * 33 + r] * scl);
        o[1] = (short)f2bf(smf[(c4 + 1) * 33 + r] * scl);
        o[2] = (short)f2bf(smf[(c4 + 2) * 33 + r] * scl);
        o[3] = (short)f2bf(smf[(c4 + 3) * 33 + r] * scl);
        *(s16x4*)&wt[((size_t)(w * D_ + n0 + r)) * D_ + k0 + c4] = o;
    } else {
        const int bid3 = bid - 5952;
        const int rp = bid3 / 6;
        const int c0 = (bid3 - rp * 6) * 128;
        const int r = t >> 7, cl = t & 127;
        for (int i = t; i < 2 * D_; i += 256) {
            const int rr = i / D_, kk = i - rr * D_;
            const int row = rp * 2 + rr;
            const int b = row >> 3, g = row & 7;
            smf[rr * D_ + kk] = hs[((size_t)b * S_ + g) * D_ + kk];
        }
        __syncthreads();
        float a0 = 0.f, a1 = 0.f, a2 = 0.f, a3 = 0.f;
        const float* wp = &Wqg[c0 + cl];
        for (int kk = 0; kk < D_; kk += 4) {
            a0 += smf[r * D_ + kk + 0] * wp[(size_t)(kk + 0) * D_];
            a1 += smf[r * D_ + kk + 1] * wp[(size_t)(kk + 1) * D_];
            a2 += smf[r * D_ + kk + 2] * wp[(size_t)(kk + 2) * D_];
            a3 += smf[r * D_ + kk + 3] * wp[(size_t)(kk + 3) * D_];
        }
        const int row = rp * 2 + r;
        qg[(size_t)row * D_ + c0 + cl] = (a0 + a1 + a2 + a3) * 0.125f;
    }
}

// ---------------------------------------------------------------------------
// Fused projection GEMM, m97-style (known-good 745 TF).
// ---------------------------------------------------------------------------
__global__ __launch_bounds__(256, 2) void proj_mfma(const ushort_t* __restrict__ A,
                                                    const ushort_t* __restrict__ Bt,
                                                    ushort_t* __restrict__ oq,
                                                    ushort_t* __restrict__ ok,
                                                    ushort_t* __restrict__ ov,
                                                    ushort_t* __restrict__ okg,
                                                    ushort_t* __restrict__ ovg) {
    __shared__ char smem[34048];
    ushort_t* Al = (ushort_t*)smem;
    ushort_t* Bl = Al + 128 * 64;

    const int t = threadIdx.x;
    const int m0 = blockIdx.x * 128;
    const int n0 = blockIdx.y * 128;
    const int lane = t & 63;
    const int w = t >> 6;
    const int wm = (w >> 1) * 64, wn = (w & 1) * 64;
    const int ln = lane & 15, hi = lane >> 4;

    const int srow_in_call = lane >> 3;
    const int scol = ((lane & 7) ^ srow_in_call) * 8;

    f32x4 acc[4][4];
#pragma unroll
    for (int mi = 0; mi < 4; ++mi)
#pragma unroll
        for (int ni = 0; ni < 4; ++ni) acc[mi][ni] = (f32x4){0.f, 0.f, 0.f, 0.f};

    for (int k0 = 0; k0 < D_; k0 += 64) {
        __syncthreads();
#pragma unroll
        for (int j = 0; j < 4; ++j) {
            const int rbase = (w * 4 + j) * 8;
            const int row = rbase + srow_in_call;
            gload16(&A[(size_t)(m0 + row) * D_ + k0 + scol], &Al[rbase * 64]);
            gload16(&Bt[(size_t)(n0 + row) * D_ + k0 + scol], &Bl[rbase * 64]);
        }
        __syncthreads();

#pragma unroll
        for (int ks = 0; ks < 2; ++ks) {
            s16x8 af[4], bf[4];
#pragma unroll
            for (int i = 0; i < 4; ++i) {
                const int ar = wm + i * 16 + ln;
                const int br = wn + i * 16 + ln;
                const int slot = (4 * ks + hi) ^ (ln & 7);
                af[i] = *(const s16x8*)&Al[ar * 64 + slot * 8];
                bf[i] = *(const s16x8*)&Bl[br * 64 + slot * 8];
            }
#pragma unroll
            for (int mi = 0; mi < 4; ++mi)
#pragma unroll
                for (int ni = 0; ni < 4; ++ni)
                    acc[mi][ni] = __builtin_amdgcn_mfma_f32_16x16x32_bf16(af[mi], bf[ni], acc[mi][ni], 0, 0, 0);
        }
    }

    float* scr = (float*)smem;
    const int rl = t >> 2, cs = (t & 3) * 32;
    const int ng = n0 + cs;
    const int w_idx = ng / D_;
    const int cb = ng - w_idx * D_;
    const int hh = cb >> 6, dd = cb & 63;
    ushort_t* dst = (w_idx == 0) ? oq : (w_idx == 1) ? ok : (w_idx == 2) ? ov
                    : (w_idx == 3) ? okg : ovg;

#pragma unroll
    for (int r = 0; r < 2; ++r) {
        __syncthreads();
        if ((w >> 1) == r) {
#pragma unroll
            for (int mi = 0; mi < 4; ++mi)
#pragma unroll
                for (int ni = 0; ni < 4; ++ni)
#pragma unroll
                    for (int rr = 0; rr < 4; ++rr)
                        scr[(mi * 16 + hi * 4 + rr) * 132 + wn + ni * 16 + ln] = acc[mi][ni][rr];
        }
        __syncthreads();
        const int m = m0 + r * 64 + rl;
        const int bb = m >> 12, s = m & 4095;
        ushort_t* drow = dst + ((size_t)(bb * H_ + hh) * S_ + s) * DH_ + dd;
        const float* srcp = scr + rl * 132 + cs;
#pragma unroll
        for (int seg = 0; seg < 4; ++seg) {
            float4 lo = *(const float4*)&srcp[seg * 8];
            float4 hi4 = *(const float4*)&srcp[seg * 8 + 4];
            s16x8 o;
            o[0] = (short)f2bf(lo.x); o[1] = (short)f2bf(lo.y);
            o[2] = (short)f2bf(lo.z); o[3] = (short)f2bf(lo.w);
            o[4] = (short)f2bf(hi4.x); o[5] = (short)f2bf(hi4.y);
            o[6] = (short)f2bf(hi4.z); o[7] = (short)f2bf(hi4.w);
            *(s16x8*)&drow[seg * 8] = o;
        }
    }
}

// ---------------------------------------------------------------------------
// Merged kernel: blocks 0..NWIN-1 = windowed attention (XCD-chunked);
// blocks NWIN.. = global-attention split-K partials (fills the win tail).
// Round-10 verified structure (142.1 us).
// ---------------------------------------------------------------------------
__global__ __launch_bounds__(256, 2) void win_glob(const ushort_t* __restrict__ q,
                                                   const ushort_t* __restrict__ k,
                                                   const ushort_t* __restrict__ v,
                                                   const float* __restrict__ am,
                                                   float* __restrict__ out,
                                                   const float* __restrict__ qg,
                                                   const ushort_t* __restrict__ kg,
                                                   const ushort_t* __restrict__ vg,
                                                   float* __restrict__ pout,
                                                   float* __restrict__ pm,
                                                   float* __restrict__ pl) {
    __shared__ char smem[39424];
    const int bid = blockIdx.x;
    const int t = threadIdx.x;

    if (bid >= NWIN) {
        // ================= global attention partials =================
        const int idx = bid - NWIN;
        const int c = idx & 63;
        const int hb = idx >> 6;
        const int h = hb % H_;
        const int b = hb / H_;
        const int bh = b * H_ + h;
        const size_t base = (size_t)bh * S_ * DH_;
        const int jg0 = c * CK_;

        float* qs = (float*)smem;                 // [8][64]
        float* kt = qs + G_ * DH_;                // [64][69]
        float* vt = kt + CK_ * 69;                // [64][68]
        float* ps = vt + CK_ * 68;                // [8][64]

        for (int i = t; i < G_ * DH_; i += 256)
            qs[(i >> 6) * DH_ + (i & 63)] = qg[(size_t)(b * G_ + (i >> 6)) * D_ + h * DH_ + (i & 63)];
        {
            const int row = t >> 2, off = (t & 3) * 16;
            const ushort_t* kr = &kg[base + (size_t)(jg0 + row) * DH_ + off];
            const ushort_t* vr = &vg[base + (size_t)(jg0 + row) * DH_ + off];
            s16x8 ka = *(const s16x8*)kr;
            s16x8 kb2 = *(const s16x8*)(kr + 8);
            s16x8 va = *(const s16x8*)vr;
            s16x8 vb = *(const s16x8*)(vr + 8);
#pragma unroll
            for (int i = 0; i < 8; ++i) {
                kt[row * 69 + off + i] = bf2f((ushort_t)ka[i]);
                kt[row * 69 + off + 8 + i] = bf2f((ushort_t)kb2[i]);
                vt[row * 68 + off + i] = bf2f((ushort_t)va[i]);
                vt[row * 68 + off + 8 + i] = bf2f((ushort_t)vb[i]);
            }
        }
        __syncthreads();

        const int g = t >> 5, jl = t & 31;
        float sc0 = 0.f, sc1 = 0.f;
#pragma unroll 8
        for (int d = 0; d < DH_; ++d) {
            const float qv = qs[g * DH_ + d];
            sc0 += qv * kt[jl * 69 + d];
            sc1 += qv * kt[(jl + 32) * 69 + d];
        }
        if (!(am[(size_t)b * S_ + jg0 + jl] > 0.5f)) sc0 = NEG_;
        if (!(am[(size_t)b * S_ + jg0 + jl + 32] > 0.5f)) sc1 = NEG_;

        float mm = fmaxf(sc0, sc1);
        mm = fmaxf(mm, __shfl_xor(mm, 1));
        mm = fmaxf(mm, __shfl_xor(mm, 2));
        mm = fmaxf(mm, __shfl_xor(mm, 4));
        mm = fmaxf(mm, __shfl_xor(mm, 8));
        mm = fmaxf(mm, __shfl_xor(mm, 16));
        const float p0 = __expf(sc0 - mm);
        const float p1 = __expf(sc1 - mm);
        float ls = p0 + p1;
        ls += __shfl_xor(ls, 1);
        ls += __shfl_xor(ls, 2);
        ls += __shfl_xor(ls, 4);
        ls += __shfl_xor(ls, 8);
        ls += __shfl_xor(ls, 16);
        ps[g * CK_ + jl] = p0;
        ps[g * CK_ + jl + 32] = p1;
        if (jl == 0) {
            pm[((size_t)bh * NC_ + c) * G_ + g] = mm;
            pl[((size_t)bh * NC_ + c) * G_ + g] = ls;
        }
        __syncthreads();

#pragma unroll
        for (int pass = 0; pass < 2; ++pass) {
            const int gg = (t >> 6) + pass * 4;
            const int d = t & 63;
            float acc = 0.f;
#pragma unroll 8
            for (int j = 0; j < CK_; ++j) acc += ps[gg * CK_ + j] * vt[j * 68 + d];
            pout[(((size_t)bh * NC_ + c) * G_ + gg) * DH_ + d] = acc;
        }
        return;
    }

    // ================= windowed attention =================
    ushort_t* Kl = (ushort_t*)smem;            // [64][72]
    ushort_t* Vt = Kl + 64 * 72;               // [64 d][66 keys]
    unsigned* Mv = (unsigned*)(Vt + 64 * 66);
    float* Ow = (float*)smem;                  // epilogue: [4 waves][32][68]

    // XCD-chunked swizzle: 768 blocks, 96 per XCD, n fastest within chunk.
    const int wg = (bid & 7) * 96 + (bid >> 3);
    const int n = wg & 31;
    const int h = (wg >> 5) % H_;
    const int b = wg / (32 * H_);

    const int lane = t & 63, w = t >> 6;
    const int l31 = lane & 31, h5 = lane >> 5;
    const int q0w = n * WQB + w * 32;
    const int q_abs = q0w + l31;
    const size_t bh = (size_t)(b * H_ + h) * S_;

    s16x8 qf[4];
#pragma unroll
    for (int ks = 0; ks < 4; ++ks)
        qf[ks] = *(const s16x8*)&q[(bh + q_abs) * DH_ + ks * 16 + 8 * h5];

    f32x16 oacc[2];
#pragma unroll
    for (int dt = 0; dt < 2; ++dt)
#pragma unroll
        for (int i = 0; i < 16; ++i) oacc[dt][i] = 0.f;
    float m_run, l_run;

    const int srow = t >> 2, soff = (t & 3) * 16;

    // ---- stage tile 0 (global keys) ----
    {
        const ushort_t* krow = &k[(bh + srow) * DH_ + soff];
        s16x8 k0v = *(const s16x8*)krow;
        s16x8 k1v = *(const s16x8*)(krow + 8);
        *(s16x8*)&Kl[srow * 72 + soff] = k0v;
        *(s16x8*)&Kl[srow * 72 + soff + 8] = k1v;
        const ushort_t* vrow = &v[(bh + srow) * DH_ + soff];
        s16x8 v0v = *(const s16x8*)vrow;
        s16x8 v1v = *(const s16x8*)(vrow + 8);
#pragma unroll
        for (int i = 0; i < 8; ++i) {
            Vt[(soff + i) * 66 + srow] = (ushort_t)v0v[i];
            Vt[(soff + 8 + i) * 66 + srow] = (ushort_t)v1v[i];
        }
    }
    __syncthreads();

    // ---- compute tile 0 (specialized: keys 0..7 -> regs 0-3 of st=0) ----
    {
        f32x16 s0;
#pragma unroll
        for (int i = 0; i < 16; ++i) s0[i] = 0.f;
#pragma unroll
        for (int ks = 0; ks < 4; ++ks) {
            s16x8 kf = *(const s16x8*)&Kl[l31 * 72 + ks * 16 + 8 * h5];
            s0 = __builtin_amdgcn_mfma_f32_32x32x16_bf16(kf, qf[ks], s0, 0, 0, 0);
        }
        float tmax = fmaxf(fmaxf(s0[0], s0[1]), fmaxf(s0[2], s0[3]));
        tmax = fmaxf(tmax, __shfl_xor(tmax, 32));
        m_run = tmax;
        float p0 = exp2f(s0[0] - m_run), p1 = exp2f(s0[1] - m_run);
        float p2 = exp2f(s0[2] - m_run), p3 = exp2f(s0[3] - m_run);
        float psum = (p0 + p1) + (p2 + p3);
        psum += __shfl_xor(psum, 32);
        l_run = psum;
        const unsigned Au = cvtpk_bf16(p0, p1);
        const unsigned Bu = cvtpk_bf16(p2, p3);
        const unsigned send0 = h5 ? Au : 0u;
        const unsigned send1 = h5 ? Bu : 0u;
        const unsigned recv0 = __shfl_xor((int)send0, 32);
        const unsigned recv1 = __shfl_xor((int)send1, 32);
        union { unsigned u[4]; s16x8 v8; } pu;
        pu.u[0] = h5 ? recv0 : Au;
        pu.u[1] = h5 ? recv1 : Bu;
        pu.u[2] = h5 ? 0u : recv0;
        pu.u[3] = h5 ? 0u : recv1;
#pragma unroll
        for (int dt = 0; dt < 2; ++dt) {
            const int vbase = (dt * 32 + l31) * 66 + 8 * h5;
            union { unsigned u[4]; s16x8 v8; } vf;
            vf.u[0] = *(const unsigned*)&Vt[vbase + 0];
            vf.u[1] = *(const unsigned*)&Vt[vbase + 2];
            vf.u[2] = *(const unsigned*)&Vt[vbase + 4];
            vf.u[3] = *(const unsigned*)&Vt[vbase + 6];
            oacc[dt] = __builtin_amdgcn_mfma_f32_32x32x16_bf16(vf.v8, pu.v8, oacc[dt], 0, 0, 0);
        }
    }

    // ---- window tiles ----
    for (int tt = 1; tt < NT_; ++tt) {
        const int pbase = n * WQB - W_ + (tt - 1) * 64;
        __syncthreads();
        {
            const int p = pbase + srow;
            const int pr = p < 0 ? 0 : (p >= S_ ? S_ - 1 : p);
            const ushort_t* krow = &k[(bh + pr) * DH_ + soff];
            s16x8 k0v = *(const s16x8*)krow;
            s16x8 k1v = *(const s16x8*)(krow + 8);
            *(s16x8*)&Kl[srow * 72 + soff] = k0v;
            *(s16x8*)&Kl[srow * 72 + soff + 8] = k1v;
            const ushort_t* vrow = &v[(bh + pr) * DH_ + soff];
            s16x8 v0v = *(const s16x8*)vrow;
            s16x8 v1v = *(const s16x8*)(vrow + 8);
#pragma unroll
            for (int i = 0; i < 8; ++i) {
                Vt[(soff + i) * 66 + srow] = (ushort_t)v0v[i];
                Vt[(soff + 8 + i) * 66 + srow] = (ushort_t)v1v[i];
            }
        }
        if (w == 0) {
            const int p2 = pbase + lane;
            const bool ok = (p2 >= G_) && (p2 < S_) &&
                            (am[(size_t)b * S_ + (p2 < 0 ? 0 : (p2 >= S_ ? S_ - 1 : p2))] > 0.5f);
            unsigned long long bal = __ballot(ok);
            if (lane == 0) { Mv[0] = (unsigned)bal; Mv[1] = (unsigned)(bal >> 32); }
        }
        __syncthreads();

        // wave-level band skip
        if (pbase > q0w + 31 + W_ || pbase + 63 < q0w - W_) continue;

        // ---- QK^T (swapped) ----
        f32x16 sc[2];
#pragma unroll
        for (int st = 0; st < 2; ++st)
#pragma unroll
            for (int i = 0; i < 16; ++i) sc[st][i] = 0.f;
#pragma unroll
        for (int st = 0; st < 2; ++st)
#pragma unroll
            for (int ks = 0; ks < 4; ++ks) {
                s16x8 kf = *(const s16x8*)&Kl[(st * 32 + l31) * 72 + ks * 16 + 8 * h5];
                sc[st] = __builtin_amdgcn_mfma_f32_32x32x16_bf16(kf, qf[ks], sc[st], 0, 0, 0);
            }

        // ---- mask (fast-path for interior tiles) + tree max ----
        const unsigned mv0 = Mv[0], mv1 = Mv[1];
        const bool fullt = ((mv0 & mv1) == 0xFFFFFFFFu) &&
                           (pbase >= q0w + 31 - W_) && (pbase + 63 <= q0w + W_);
        if (!fullt) {
#pragma unroll
            for (int st = 0; st < 2; ++st)
#pragma unroll
                for (int reg = 0; reg < 16; ++reg) {
                    const int cst = (reg & 3) + 8 * (reg >> 2);
                    const int crow = cst + 4 * h5;
                    const int key_abs = pbase + st * 32 + crow;
                    const unsigned mvx = (st == 0) ? mv0 : mv1;
                    const bool valid = ((mvx >> crow) & 1u) &&
                                       (key_abs >= q_abs - W_) && (key_abs <= q_abs + W_);
                    sc[st][reg] = valid ? sc[st][reg] : -1e30f;
                }
        }
        float tmax = fmaxf(vmax16f(sc[0]), vmax16f(sc[1]));
        tmax = fmaxf(tmax, __shfl_xor(tmax, 32));

        // ---- defer-max online softmax (exp2 domain) ----
        if (__any(tmax > m_run + 11.5f)) {
            const float mnew = fmaxf(m_run, tmax);
            const float f = exp2f(m_run - mnew);
            l_run *= f;
#pragma unroll
            for (int dt = 0; dt < 2; ++dt)
#pragma unroll
                for (int i = 0; i < 16; ++i) oacc[dt][i] *= f;
            m_run = mnew;
        }
#pragma unroll
        for (int st = 0; st < 2; ++st)
#pragma unroll
            for (int reg = 0; reg < 16; ++reg)
                sc[st][reg] = exp2f(sc[st][reg] - m_run);
        float psum = vsum16f(sc[0]) + vsum16f(sc[1]);
        psum += __shfl_xor(psum, 32);
        l_run += psum;

        // ---- P -> bf16 B-fragments + PV ----
#pragma unroll
        for (int ks = 0; ks < 4; ++ks) {
            const int st = ks >> 1, k8 = (ks & 1) * 8;
            const unsigned Au = cvtpk_bf16(sc[st][k8 + 0], sc[st][k8 + 1]);
            const unsigned Bu = cvtpk_bf16(sc[st][k8 + 2], sc[st][k8 + 3]);
            const unsigned Cu = cvtpk_bf16(sc[st][k8 + 4], sc[st][k8 + 5]);
            const unsigned Du = cvtpk_bf16(sc[st][k8 + 6], sc[st][k8 + 7]);
            const unsigned send0 = h5 ? Au : Cu;
            const unsigned send1 = h5 ? Bu : Du;
            const unsigned recv0 = __shfl_xor((int)send0, 32);
            const unsigned recv1 = __shfl_xor((int)send1, 32);
            union { unsigned u[4]; s16x8 v8; } pu;
            pu.u[0] = h5 ? recv0 : Au;
            pu.u[1] = h5 ? recv1 : Bu;
            pu.u[2] = h5 ? Cu : recv0;
            pu.u[3] = h5 ? Du : recv1;
#pragma unroll
            for (int dt = 0; dt < 2; ++dt) {
                const int vbase = (dt * 32 + l31) * 66 + ks * 16 + 8 * h5;
                union { unsigned u[4]; s16x8 v8; } vf;
                vf.u[0] = *(const unsigned*)&Vt[vbase + 0];
                vf.u[1] = *(const unsigned*)&Vt[vbase + 2];
                vf.u[2] = *(const unsigned*)&Vt[vbase + 4];
                vf.u[3] = *(const unsigned*)&Vt[vbase + 6];
                oacc[dt] = __builtin_amdgcn_mfma_f32_32x32x16_bf16(vf.v8, pu.v8, oacc[dt], 0, 0, 0);
            }
        }
    }

    // ---- epilogue: O^T -> O via LDS, coalesced store ----
    __syncthreads();
    const float inv = 1.0f / l_run;
    float* OwW = Ow + w * 32 * 68;
#pragma unroll
    for (int dt = 0; dt < 2; ++dt)
#pragma unroll
        for (int reg = 0; reg < 16; ++reg) {
            const int d = dt * 32 + (reg & 3) + 8 * (reg >> 2) + 4 * h5;
            OwW[l31 * 68 + d] = oacc[dt][reg] * inv;
        }
    asm volatile("s_waitcnt lgkmcnt(0)" ::: "memory");
    const int qq = lane >> 1, half = lane & 1;
    const float* src = &OwW[qq * 68 + half * 32];
    float* dstp = &out[((size_t)b * S_ + q0w + qq) * D_ + h * DH_ + half * 32];
#pragma unroll
    for (int j = 0; j < 8; ++j)
        *(float4*)&dstp[j * 4] = *(const float4*)&src[j * 4];
}

// ---------------------------------------------------------------------------
// Global attention phase B: combine chunks (overwrites first-G rows, last).
// ---------------------------------------------------------------------------
__global__ __launch_bounds__(256) void glob_reduce(const float* __restrict__ pout,
                                                   const float* __restrict__ pm,
                                                   const float* __restrict__ pl,
                                                   float* __restrict__ out) {
    const int bh = blockIdx.x;
    const int b = bh / H_, h = bh - b * H_;
    const int t = threadIdx.x;

    __shared__ float wc[G_][NC_];
    __shared__ float wsum[G_];

    const int g = t >> 5, cl = t & 31;
    const float m0 = pm[((size_t)bh * NC_ + cl) * G_ + g];
    const float m1 = pm[((size_t)bh * NC_ + cl + 32) * G_ + g];
    float M = fmaxf(m0, m1);
    M = fmaxf(M, __shfl_xor(M, 1));
    M = fmaxf(M, __shfl_xor(M, 2));
    M = fmaxf(M, __shfl_xor(M, 4));
    M = fmaxf(M, __shfl_xor(M, 8));
    M = fmaxf(M, __shfl_xor(M, 16));
    const float w0 = __expf(m0 - M);
    const float w1 = __expf(m1 - M);
    float S = w0 * pl[((size_t)bh * NC_ + cl) * G_ + g] +
              w1 * pl[((size_t)bh * NC_ + cl + 32) * G_ + g];
    S += __shfl_xor(S, 1);
    S += __shfl_xor(S, 2);
    S += __shfl_xor(S, 4);
    S += __shfl_xor(S, 8);
    S += __shfl_xor(S, 16);
    wc[g][cl] = w0;
    wc[g][cl + 32] = w1;
    if (cl == 0) wsum[g] = S;
    __syncthreads();

#pragma unroll
    for (int pass = 0; pass < 2; ++pass) {
        const int gg = (t >> 6) + pass * 4;
        const int d = t & 63;
        float acc = 0.f;
        for (int c2 = 0; c2 < NC_; ++c2)
            acc += wc[gg][c2] * pout[(((size_t)bh * NC_ + c2) * G_ + gg) * DH_ + d];
        out[((size_t)b * S_ + gg) * D_ + h * DH_ + d] = acc / wsum[gg];
    }
}

// ---------------------------------------------------------------------------
extern "C" void kernel_launch(void* const* d_in, const int* in_sizes, int n_in,
                              void* d_out, int out_size, void* d_ws, size_t ws_size,
                              hipStream_t stream) {
    (void)in_sizes; (void)n_in; (void)out_size; (void)ws_size;

    const float* hs    = (const float*)d_in[0];
    const float* amask = (const float*)d_in[1];
    const float* Wq    = (const float*)d_in[2];
    const float* Wk    = (const float*)d_in[3];
    const float* Wv    = (const float*)d_in[4];
    const float* Wqg   = (const float*)d_in[5];
    const float* Wkg   = (const float*)d_in[6];
    const float* Wvg   = (const float*)d_in[7];
    float* out = (float*)d_out;

    char* p = (char*)d_ws;
    ushort_t* hs_bf = (ushort_t*)p; p += (size_t)B_ * S_ * D_ * 2;
    ushort_t* wt    = (ushort_t*)p; p += (size_t)5 * D_ * D_ * 2;
    const size_t per = (size_t)B_ * H_ * S_ * DH_;
    ushort_t* qb  = (ushort_t*)p; p += per * 2;
    ushort_t* kb  = (ushort_t*)p; p += per * 2;
    ushort_t* vb  = (ushort_t*)p; p += per * 2;
    ushort_t* kgb = (ushort_t*)p; p += per * 2;
    ushort_t* vgb = (ushort_t*)p; p += per * 2;
    float* qg   = (float*)p; p += (size_t)B_ * G_ * D_ * 4;
    float* pout = (float*)p; p += (size_t)B_ * H_ * NC_ * G_ * DH_ * 4;
    float* pm   = (float*)p; p += (size_t)B_ * H_ * NC_ * G_ * 4;
    float* pl   = (float*)p;

    fused_pre<<<6000, 256, 0, stream>>>(hs, Wq, Wk, Wv, Wkg, Wvg, Wqg, hs_bf, wt, qg);
    proj_mfma<<<dim3(B_ * S_ / 128, 5 * D_ / 128), 256, 0, stream>>>(hs_bf, wt, qb, kb, vb, kgb, vgb);
    win_glob<<<NWIN + NC_ * H_ * B_, 256, 0, stream>>>(qb, kb, vb, amask, out,
                                                       qg, kgb, vgb, pout, pm, pl);
    glob_reduce<<<B_ * H_, 256, 0, stream>>>(pout, pm, pl, out);
}

// Round 13
// 140.292 us; speedup vs baseline: 1.0794x; 1.0118x over previous
//
#include <hip/hip_runtime.h>

#define B_ 2
#define S_ 4096
#define D_ 768
#define H_ 12
#define DH_ 64
#define W_ 256
#define G_ 8
#define NEG_ (-1e9f)
#define NC_ 64
#define CK_ 64
#define WQB 128
#define NT_ 11
#define NWIN (B_ * H_ * (S_ / WQB))   // 768 win blocks

typedef __attribute__((ext_vector_type(4))) float f32x4;
typedef __attribute__((ext_vector_type(16))) float f32x16;
typedef __attribute__((ext_vector_type(8))) short s16x8;
typedef __attribute__((ext_vector_type(4))) short s16x4;
typedef unsigned short ushort_t;

__device__ __forceinline__ unsigned short f2bf(float f) {
    union { float f; unsigned u; } v; v.f = f;
    unsigned r = v.u + 0x7FFFu + ((v.u >> 16) & 1u);
    return (unsigned short)(r >> 16);
}
__device__ __forceinline__ float bf2f(unsigned short b) {
    union { unsigned u; float f; } v; v.u = ((unsigned)b) << 16;
    return v.f;
}
__device__ __forceinline__ float bfbits(unsigned u) {
    union { unsigned u; float f; } v; v.u = u;
    return v.f;
}
__device__ __forceinline__ unsigned cvtpk_bf16(float lo, float hi) {
    unsigned r;
    asm("v_cvt_pk_bf16_f32 %0, %1, %2" : "=v"(r) : "v"(lo), "v"(hi));
    return r;
}
__device__ __forceinline__ void gload16(const ushort_t* g, ushort_t* l) {
    __builtin_amdgcn_global_load_lds(
        (const __attribute__((address_space(1))) unsigned*)g,
        (__attribute__((address_space(3))) unsigned*)l, 16, 0, 0);
}
__device__ __forceinline__ float vmax16f(f32x16 v) {
    float a0 = fmaxf(v[0], v[1]), a1 = fmaxf(v[2], v[3]);
    float a2 = fmaxf(v[4], v[5]), a3 = fmaxf(v[6], v[7]);
    float a4 = fmaxf(v[8], v[9]), a5 = fmaxf(v[10], v[11]);
    float a6 = fmaxf(v[12], v[13]), a7 = fmaxf(v[14], v[15]);
    return fmaxf(fmaxf(fmaxf(a0, a1), fmaxf(a2, a3)),
                 fmaxf(fmaxf(a4, a5), fmaxf(a6, a7)));
}
__device__ __forceinline__ float vsum16f(f32x16 v) {
    float a0 = v[0] + v[1], a1 = v[2] + v[3];
    float a2 = v[4] + v[5], a3 = v[6] + v[7];
    float a4 = v[8] + v[9], a5 = v[10] + v[11];
    float a6 = v[12] + v[13], a7 = v[14] + v[15];
    return ((a0 + a1) + (a2 + a3)) + ((a4 + a5) + (a6 + a7));
}

// ---------------------------------------------------------------------------
// Fused prologue: hs->bf16 (blocks 0..3071), weight transpose+convert
// (blocks 3072..5951), qg GEMM (blocks 5952..5999).
// ---------------------------------------------------------------------------
__global__ __launch_bounds__(256) void fused_pre(const float* __restrict__ hs,
                                                 const float* __restrict__ W0,
                                                 const float* __restrict__ W1,
                                                 const float* __restrict__ W2,
                                                 const float* __restrict__ W3,
                                                 const float* __restrict__ W4,
                                                 const float* __restrict__ Wqg,
                                                 ushort_t* __restrict__ hs_bf,
                                                 ushort_t* __restrict__ wt,
                                                 float* __restrict__ qg) {
    __shared__ float smf[2 * D_];
    const int bid = blockIdx.x;
    const int t = threadIdx.x;

    if (bid < 3072) {
        const int i = bid * 256 + t;
        float4 a = *(const float4*)&hs[(size_t)i * 8];
        float4 c = *(const float4*)&hs[(size_t)i * 8 + 4];
        s16x8 o;
        o[0] = (short)f2bf(a.x); o[1] = (short)f2bf(a.y);
        o[2] = (short)f2bf(a.z); o[3] = (short)f2bf(a.w);
        o[4] = (short)f2bf(c.x); o[5] = (short)f2bf(c.y);
        o[6] = (short)f2bf(c.z); o[7] = (short)f2bf(c.w);
        *(s16x8*)&hs_bf[(size_t)i * 8] = o;
    } else if (bid < 5952) {
        const int bid2 = bid - 3072;
        const int w = bid2 / 576;
        const int rem = bid2 - w * 576;
        const int k0 = (rem / 24) * 32;
        const int n0 = (rem % 24) * 32;
        const float* Wsrc = (w == 0) ? W0 : (w == 1) ? W1 : (w == 2) ? W2 : (w == 3) ? W3 : W4;
        const float scl = (w == 0) ? 0.125f * 1.44269504f : 1.0f;   // Wq in exp2 domain
        const int r = t >> 3, c4 = (t & 7) * 4;
        float4 src = *(const float4*)&Wsrc[(size_t)(k0 + r) * D_ + n0 + c4];
        smf[r * 33 + c4 + 0] = src.x; smf[r * 33 + c4 + 1] = src.y;
        smf[r * 33 + c4 + 2] = src.z; smf[r * 33 + c4 + 3] = src.w;
        __syncthreads();
        s16x4 o;
        o[0] = (short)f2bf(smf[(c4 + 0) * 33 + r] * scl);
        o[1] = (short)f2bf(smf[(c4 + 1) * 33 + r] * scl);
        o[2] = (short)f2bf(smf[(c4 + 2) * 33 + r] * scl);
        o[3] = (short)f2bf(smf[(c4 + 3) * 33 + r] * scl);
        *(s16x4*)&wt[((size_t)(w * D_ + n0 + r)) * D_ + k0 + c4] = o;
    } else {
        const int bid3 = bid - 5952;
        const int rp = bid3 / 6;
        const int c0 = (bid3 - rp * 6) * 128;
        const int r = t >> 7, cl = t & 127;
        for (int i = t; i < 2 * D_; i += 256) {
            const int rr = i / D_, kk = i - rr * D_;
            const int row = rp * 2 + rr;
            const int b = row >> 3, g = row & 7;
            smf[rr * D_ + kk] = hs[((size_t)b * S_ + g) * D_ + kk];
        }
        __syncthreads();
        float a0 = 0.f, a1 = 0.f, a2 = 0.f, a3 = 0.f;
        const float* wp = &Wqg[c0 + cl];
        for (int kk = 0; kk < D_; kk += 4) {
            a0 += smf[r * D_ + kk + 0] * wp[(size_t)(kk + 0) * D_];
            a1 += smf[r * D_ + kk + 1] * wp[(size_t)(kk + 1) * D_];
            a2 += smf[r * D_ + kk + 2] * wp[(size_t)(kk + 2) * D_];
            a3 += smf[r * D_ + kk + 3] * wp[(size_t)(kk + 3) * D_];
        }
        const int row = rp * 2 + r;
        qg[(size_t)row * D_ + c0 + cl] = (a0 + a1 + a2 + a3) * 0.125f;
    }
}

// ---------------------------------------------------------------------------
// Fused projection GEMM, m97-style (known-good 745 TF).
// ---------------------------------------------------------------------------
__global__ __launch_bounds__(256, 2) void proj_mfma(const ushort_t* __restrict__ A,
                                                    const ushort_t* __restrict__ Bt,
                                                    ushort_t* __restrict__ oq,
                                                    ushort_t* __restrict__ ok,
                                                    ushort_t* __restrict__ ov,
                                                    ushort_t* __restrict__ okg,
                                                    ushort_t* __restrict__ ovg) {
    __shared__ char smem[34048];
    ushort_t* Al = (ushort_t*)smem;
    ushort_t* Bl = Al + 128 * 64;

    const int t = threadIdx.x;
    const int m0 = blockIdx.x * 128;
    const int n0 = blockIdx.y * 128;
    const int lane = t & 63;
    const int w = t >> 6;
    const int wm = (w >> 1) * 64, wn = (w & 1) * 64;
    const int ln = lane & 15, hi = lane >> 4;

    const int srow_in_call = lane >> 3;
    const int scol = ((lane & 7) ^ srow_in_call) * 8;

    f32x4 acc[4][4];
#pragma unroll
    for (int mi = 0; mi < 4; ++mi)
#pragma unroll
        for (int ni = 0; ni < 4; ++ni) acc[mi][ni] = (f32x4){0.f, 0.f, 0.f, 0.f};

    for (int k0 = 0; k0 < D_; k0 += 64) {
        __syncthreads();
#pragma unroll
        for (int j = 0; j < 4; ++j) {
            const int rbase = (w * 4 + j) * 8;
            const int row = rbase + srow_in_call;
            gload16(&A[(size_t)(m0 + row) * D_ + k0 + scol], &Al[rbase * 64]);
            gload16(&Bt[(size_t)(n0 + row) * D_ + k0 + scol], &Bl[rbase * 64]);
        }
        __syncthreads();

#pragma unroll
        for (int ks = 0; ks < 2; ++ks) {
            s16x8 af[4], bf[4];
#pragma unroll
            for (int i = 0; i < 4; ++i) {
                const int ar = wm + i * 16 + ln;
                const int br = wn + i * 16 + ln;
                const int slot = (4 * ks + hi) ^ (ln & 7);
                af[i] = *(const s16x8*)&Al[ar * 64 + slot * 8];
                bf[i] = *(const s16x8*)&Bl[br * 64 + slot * 8];
            }
#pragma unroll
            for (int mi = 0; mi < 4; ++mi)
#pragma unroll
                for (int ni = 0; ni < 4; ++ni)
                    acc[mi][ni] = __builtin_amdgcn_mfma_f32_16x16x32_bf16(af[mi], bf[ni], acc[mi][ni], 0, 0, 0);
        }
    }

    float* scr = (float*)smem;
    const int rl = t >> 2, cs = (t & 3) * 32;
    const int ng = n0 + cs;
    const int w_idx = ng / D_;
    const int cb = ng - w_idx * D_;
    const int hh = cb >> 6, dd = cb & 63;
    ushort_t* dst = (w_idx == 0) ? oq : (w_idx == 1) ? ok : (w_idx == 2) ? ov
                    : (w_idx == 3) ? okg : ovg;

#pragma unroll
    for (int r = 0; r < 2; ++r) {
        __syncthreads();
        if ((w >> 1) == r) {
#pragma unroll
            for (int mi = 0; mi < 4; ++mi)
#pragma unroll
                for (int ni = 0; ni < 4; ++ni)
#pragma unroll
                    for (int rr = 0; rr < 4; ++rr)
                        scr[(mi * 16 + hi * 4 + rr) * 132 + wn + ni * 16 + ln] = acc[mi][ni][rr];
        }
        __syncthreads();
        const int m = m0 + r * 64 + rl;
        const int bb = m >> 12, s = m & 4095;
        ushort_t* drow = dst + ((size_t)(bb * H_ + hh) * S_ + s) * DH_ + dd;
        const float* srcp = scr + rl * 132 + cs;
#pragma unroll
        for (int seg = 0; seg < 4; ++seg) {
            float4 lo = *(const float4*)&srcp[seg * 8];
            float4 hi4 = *(const float4*)&srcp[seg * 8 + 4];
            s16x8 o;
            o[0] = (short)f2bf(lo.x); o[1] = (short)f2bf(lo.y);
            o[2] = (short)f2bf(lo.z); o[3] = (short)f2bf(lo.w);
            o[4] = (short)f2bf(hi4.x); o[5] = (short)f2bf(hi4.y);
            o[6] = (short)f2bf(hi4.z); o[7] = (short)f2bf(hi4.w);
            *(s16x8*)&drow[seg * 8] = o;
        }
    }
}

// ---------------------------------------------------------------------------
// Merged kernel (r10 structure), LDS shrunk 39424 -> 22016 B for occupancy:
//  - glob path stages K/V as raw bf16 (kt stride 74: 37*jl mod 32 coprime ->
//    conflict-free score reads; vt stride 66: broadcast reads)
//  - win epilogue uses a 2-wave buffer in 2 rounds (17.4 KB)
// Win hot loop is UNCHANGED.  4 -> 6 blocks/CU (VGPR-80 capped).
// ---------------------------------------------------------------------------
__global__ __launch_bounds__(256, 2) void win_glob(const ushort_t* __restrict__ q,
                                                   const ushort_t* __restrict__ k,
                                                   const ushort_t* __restrict__ v,
                                                   const float* __restrict__ am,
                                                   float* __restrict__ out,
                                                   const float* __restrict__ qg,
                                                   const ushort_t* __restrict__ kg,
                                                   const ushort_t* __restrict__ vg,
                                                   float* __restrict__ pout,
                                                   float* __restrict__ pm,
                                                   float* __restrict__ pl) {
    __shared__ __align__(16) char smem[22016];
    const int bid = blockIdx.x;
    const int t = threadIdx.x;

    if (bid >= NWIN) {
        // ================= global attention partials (bf16 LDS) ===========
        const int idx = bid - NWIN;
        const int c = idx & 63;
        const int hb = idx >> 6;
        const int h = hb % H_;
        const int b = hb / H_;
        const int bh = b * H_ + h;
        const size_t base = (size_t)bh * S_ * DH_;
        const int jg0 = c * CK_;

        float* qs = (float*)smem;                              // 2048 B
        ushort_t* kt = (ushort_t*)(smem + 2048);               // [64][74] = 9472 B
        ushort_t* vt = (ushort_t*)(smem + 2048 + 9472);        // [64][66] = 8448 B
        float* ps = (float*)(smem + 2048 + 9472 + 8448);       // 2048 B

        for (int i = t; i < G_ * DH_; i += 256)
            qs[(i >> 6) * DH_ + (i & 63)] = qg[(size_t)(b * G_ + (i >> 6)) * D_ + h * DH_ + (i & 63)];
        {
            const int row = t >> 2, off = (t & 3) * 16;
            const ushort_t* kr = &kg[base + (size_t)(jg0 + row) * DH_ + off];
            const ushort_t* vr = &vg[base + (size_t)(jg0 + row) * DH_ + off];
            union { s16x8 v8; unsigned u[4]; } a0, a1, b0, b1;
            a0.v8 = *(const s16x8*)kr;
            a1.v8 = *(const s16x8*)(kr + 8);
            b0.v8 = *(const s16x8*)vr;
            b1.v8 = *(const s16x8*)(vr + 8);
            unsigned* kd = (unsigned*)&kt[row * 74 + off];
            unsigned* vd = (unsigned*)&vt[row * 66 + off];
#pragma unroll
            for (int i = 0; i < 4; ++i) {
                kd[i] = a0.u[i];
                kd[4 + i] = a1.u[i];
                vd[i] = b0.u[i];
                vd[4 + i] = b1.u[i];
            }
        }
        __syncthreads();

        const int g = t >> 5, jl = t & 31;
        float sc0 = 0.f, sc1 = 0.f;
#pragma unroll 8
        for (int d = 0; d < DH_; d += 2) {
            const unsigned k0p = *(const unsigned*)&kt[jl * 74 + d];
            const unsigned k1p = *(const unsigned*)&kt[(jl + 32) * 74 + d];
            const float q0v = qs[g * DH_ + d];
            const float q1v = qs[g * DH_ + d + 1];
            sc0 += q0v * bfbits(k0p << 16) + q1v * bfbits(k0p & 0xFFFF0000u);
            sc1 += q0v * bfbits(k1p << 16) + q1v * bfbits(k1p & 0xFFFF0000u);
        }
        if (!(am[(size_t)b * S_ + jg0 + jl] > 0.5f)) sc0 = NEG_;
        if (!(am[(size_t)b * S_ + jg0 + jl + 32] > 0.5f)) sc1 = NEG_;

        float mm = fmaxf(sc0, sc1);
        mm = fmaxf(mm, __shfl_xor(mm, 1));
        mm = fmaxf(mm, __shfl_xor(mm, 2));
        mm = fmaxf(mm, __shfl_xor(mm, 4));
        mm = fmaxf(mm, __shfl_xor(mm, 8));
        mm = fmaxf(mm, __shfl_xor(mm, 16));
        const float p0 = __expf(sc0 - mm);
        const float p1 = __expf(sc1 - mm);
        float ls = p0 + p1;
        ls += __shfl_xor(ls, 1);
        ls += __shfl_xor(ls, 2);
        ls += __shfl_xor(ls, 4);
        ls += __shfl_xor(ls, 8);
        ls += __shfl_xor(ls, 16);
        ps[g * CK_ + jl] = p0;
        ps[g * CK_ + jl + 32] = p1;
        if (jl == 0) {
            pm[((size_t)bh * NC_ + c) * G_ + g] = mm;
            pl[((size_t)bh * NC_ + c) * G_ + g] = ls;
        }
        __syncthreads();

#pragma unroll
        for (int pass = 0; pass < 2; ++pass) {
            const int gg = (t >> 6) + pass * 4;
            const int d = t & 63;
            float acc = 0.f;
#pragma unroll 8
            for (int j = 0; j < CK_; ++j) acc += ps[gg * CK_ + j] * bf2f(vt[j * 66 + d]);
            pout[(((size_t)bh * NC_ + c) * G_ + gg) * DH_ + d] = acc;
        }
        return;
    }

    // ================= windowed attention (hot loop unchanged) ============
    ushort_t* Kl = (ushort_t*)smem;            // [64][72] = 9216 B
    ushort_t* Vt = Kl + 64 * 72;               // [64 d][66 keys] = 8448 B
    unsigned* Mv = (unsigned*)(Vt + 64 * 66);
    float* Ow = (float*)smem;                  // epilogue: [2 waves][32][68] = 17408 B

    // XCD-chunked swizzle: 768 blocks, 96 per XCD, n fastest within chunk.
    const int wg = (bid & 7) * 96 + (bid >> 3);
    const int n = wg & 31;
    const int h = (wg >> 5) % H_;
    const int b = wg / (32 * H_);

    const int lane = t & 63, w = t >> 6;
    const int l31 = lane & 31, h5 = lane >> 5;
    const int q0w = n * WQB + w * 32;
    const int q_abs = q0w + l31;
    const size_t bh = (size_t)(b * H_ + h) * S_;

    s16x8 qf[4];
#pragma unroll
    for (int ks = 0; ks < 4; ++ks)
        qf[ks] = *(const s16x8*)&q[(bh + q_abs) * DH_ + ks * 16 + 8 * h5];

    f32x16 oacc[2];
#pragma unroll
    for (int dt = 0; dt < 2; ++dt)
#pragma unroll
        for (int i = 0; i < 16; ++i) oacc[dt][i] = 0.f;
    float m_run, l_run;

    const int srow = t >> 2, soff = (t & 3) * 16;

    // ---- stage tile 0 (global keys) ----
    {
        const ushort_t* krow = &k[(bh + srow) * DH_ + soff];
        s16x8 k0v = *(const s16x8*)krow;
        s16x8 k1v = *(const s16x8*)(krow + 8);
        *(s16x8*)&Kl[srow * 72 + soff] = k0v;
        *(s16x8*)&Kl[srow * 72 + soff + 8] = k1v;
        const ushort_t* vrow = &v[(bh + srow) * DH_ + soff];
        s16x8 v0v = *(const s16x8*)vrow;
        s16x8 v1v = *(const s16x8*)(vrow + 8);
#pragma unroll
        for (int i = 0; i < 8; ++i) {
            Vt[(soff + i) * 66 + srow] = (ushort_t)v0v[i];
            Vt[(soff + 8 + i) * 66 + srow] = (ushort_t)v1v[i];
        }
    }
    __syncthreads();

    // ---- compute tile 0 (specialized: keys 0..7 -> regs 0-3 of st=0) ----
    {
        f32x16 s0;
#pragma unroll
        for (int i = 0; i < 16; ++i) s0[i] = 0.f;
#pragma unroll
        for (int ks = 0; ks < 4; ++ks) {
            s16x8 kf = *(const s16x8*)&Kl[l31 * 72 + ks * 16 + 8 * h5];
            s0 = __builtin_amdgcn_mfma_f32_32x32x16_bf16(kf, qf[ks], s0, 0, 0, 0);
        }
        float tmax = fmaxf(fmaxf(s0[0], s0[1]), fmaxf(s0[2], s0[3]));
        tmax = fmaxf(tmax, __shfl_xor(tmax, 32));
        m_run = tmax;
        float p0 = exp2f(s0[0] - m_run), p1 = exp2f(s0[1] - m_run);
        float p2 = exp2f(s0[2] - m_run), p3 = exp2f(s0[3] - m_run);
        float psum = (p0 + p1) + (p2 + p3);
        psum += __shfl_xor(psum, 32);
        l_run = psum;
        const unsigned Au = cvtpk_bf16(p0, p1);
        const unsigned Bu = cvtpk_bf16(p2, p3);
        const unsigned send0 = h5 ? Au : 0u;
        const unsigned send1 = h5 ? Bu : 0u;
        const unsigned recv0 = __shfl_xor((int)send0, 32);
        const unsigned recv1 = __shfl_xor((int)send1, 32);
        union { unsigned u[4]; s16x8 v8; } pu;
        pu.u[0] = h5 ? recv0 : Au;
        pu.u[1] = h5 ? recv1 : Bu;
        pu.u[2] = h5 ? 0u : recv0;
        pu.u[3] = h5 ? 0u : recv1;
#pragma unroll
        for (int dt = 0; dt < 2; ++dt) {
            const int vbase = (dt * 32 + l31) * 66 + 8 * h5;
            union { unsigned u[4]; s16x8 v8; } vf;
            vf.u[0] = *(const unsigned*)&Vt[vbase + 0];
            vf.u[1] = *(const unsigned*)&Vt[vbase + 2];
            vf.u[2] = *(const unsigned*)&Vt[vbase + 4];
            vf.u[3] = *(const unsigned*)&Vt[vbase + 6];
            oacc[dt] = __builtin_amdgcn_mfma_f32_32x32x16_bf16(vf.v8, pu.v8, oacc[dt], 0, 0, 0);
        }
    }

    // ---- window tiles ----
    for (int tt = 1; tt < NT_; ++tt) {
        const int pbase = n * WQB - W_ + (tt - 1) * 64;
        __syncthreads();
        {
            const int p = pbase + srow;
            const int pr = p < 0 ? 0 : (p >= S_ ? S_ - 1 : p);
            const ushort_t* krow = &k[(bh + pr) * DH_ + soff];
            s16x8 k0v = *(const s16x8*)krow;
            s16x8 k1v = *(const s16x8*)(krow + 8);
            *(s16x8*)&Kl[srow * 72 + soff] = k0v;
            *(s16x8*)&Kl[srow * 72 + soff + 8] = k1v;
            const ushort_t* vrow = &v[(bh + pr) * DH_ + soff];
            s16x8 v0v = *(const s16x8*)vrow;
            s16x8 v1v = *(const s16x8*)(vrow + 8);
#pragma unroll
            for (int i = 0; i < 8; ++i) {
                Vt[(soff + i) * 66 + srow] = (ushort_t)v0v[i];
                Vt[(soff + 8 + i) * 66 + srow] = (ushort_t)v1v[i];
            }
        }
        if (w == 0) {
            const int p2 = pbase + lane;
            const bool ok = (p2 >= G_) && (p2 < S_) &&
                            (am[(size_t)b * S_ + (p2 < 0 ? 0 : (p2 >= S_ ? S_ - 1 : p2))] > 0.5f);
            unsigned long long bal = __ballot(ok);
            if (lane == 0) { Mv[0] = (unsigned)bal; Mv[1] = (unsigned)(bal >> 32); }
        }
        __syncthreads();

        // wave-level band skip
        if (pbase > q0w + 31 + W_ || pbase + 63 < q0w - W_) continue;

        // ---- QK^T (swapped) ----
        f32x16 sc[2];
#pragma unroll
        for (int st = 0; st < 2; ++st)
#pragma unroll
            for (int i = 0; i < 16; ++i) sc[st][i] = 0.f;
#pragma unroll
        for (int st = 0; st < 2; ++st)
#pragma unroll
            for (int ks = 0; ks < 4; ++ks) {
                s16x8 kf = *(const s16x8*)&Kl[(st * 32 + l31) * 72 + ks * 16 + 8 * h5];
                sc[st] = __builtin_amdgcn_mfma_f32_32x32x16_bf16(kf, qf[ks], sc[st], 0, 0, 0);
            }

        // ---- mask (fast-path for interior tiles) + tree max ----
        const unsigned mv0 = Mv[0], mv1 = Mv[1];
        const bool fullt = ((mv0 & mv1) == 0xFFFFFFFFu) &&
                           (pbase >= q0w + 31 - W_) && (pbase + 63 <= q0w + W_);
        if (!fullt) {
#pragma unroll
            for (int st = 0; st < 2; ++st)
#pragma unroll
                for (int reg = 0; reg < 16; ++reg) {
                    const int cst = (reg & 3) + 8 * (reg >> 2);
                    const int crow = cst + 4 * h5;
                    const int key_abs = pbase + st * 32 + crow;
                    const unsigned mvx = (st == 0) ? mv0 : mv1;
                    const bool valid = ((mvx >> crow) & 1u) &&
                                       (key_abs >= q_abs - W_) && (key_abs <= q_abs + W_);
                    sc[st][reg] = valid ? sc[st][reg] : -1e30f;
                }
        }
        float tmax = fmaxf(vmax16f(sc[0]), vmax16f(sc[1]));
        tmax = fmaxf(tmax, __shfl_xor(tmax, 32));

        // ---- defer-max online softmax (exp2 domain) ----
        if (__any(tmax > m_run + 11.5f)) {
            const float mnew = fmaxf(m_run, tmax);
            const float f = exp2f(m_run - mnew);
            l_run *= f;
#pragma unroll
            for (int dt = 0; dt < 2; ++dt)
#pragma unroll
                for (int i = 0; i < 16; ++i) oacc[dt][i] *= f;
            m_run = mnew;
        }
#pragma unroll
        for (int st = 0; st < 2; ++st)
#pragma unroll
            for (int reg = 0; reg < 16; ++reg)
                sc[st][reg] = exp2f(sc[st][reg] - m_run);
        float psum = vsum16f(sc[0]) + vsum16f(sc[1]);
        psum += __shfl_xor(psum, 32);
        l_run += psum;

        // ---- P -> bf16 B-fragments + PV ----
#pragma unroll
        for (int ks = 0; ks < 4; ++ks) {
            const int st = ks >> 1, k8 = (ks & 1) * 8;
            const unsigned Au = cvtpk_bf16(sc[st][k8 + 0], sc[st][k8 + 1]);
            const unsigned Bu = cvtpk_bf16(sc[st][k8 + 2], sc[st][k8 + 3]);
            const unsigned Cu = cvtpk_bf16(sc[st][k8 + 4], sc[st][k8 + 5]);
            const unsigned Du = cvtpk_bf16(sc[st][k8 + 6], sc[st][k8 + 7]);
            const unsigned send0 = h5 ? Au : Cu;
            const unsigned send1 = h5 ? Bu : Du;
            const unsigned recv0 = __shfl_xor((int)send0, 32);
            const unsigned recv1 = __shfl_xor((int)send1, 32);
            union { unsigned u[4]; s16x8 v8; } pu;
            pu.u[0] = h5 ? recv0 : Au;
            pu.u[1] = h5 ? recv1 : Bu;
            pu.u[2] = h5 ? Cu : recv0;
            pu.u[3] = h5 ? Du : recv1;
#pragma unroll
            for (int dt = 0; dt < 2; ++dt) {
                const int vbase = (dt * 32 + l31) * 66 + ks * 16 + 8 * h5;
                union { unsigned u[4]; s16x8 v8; } vf;
                vf.u[0] = *(const unsigned*)&Vt[vbase + 0];
                vf.u[1] = *(const unsigned*)&Vt[vbase + 2];
                vf.u[2] = *(const unsigned*)&Vt[vbase + 4];
                vf.u[3] = *(const unsigned*)&Vt[vbase + 6];
                oacc[dt] = __builtin_amdgcn_mfma_f32_32x32x16_bf16(vf.v8, pu.v8, oacc[dt], 0, 0, 0);
            }
        }
    }

    // ---- epilogue: 2 rounds of 2 waves through a 17.4 KB buffer ----
    const float inv = 1.0f / l_run;
    __syncthreads();
    if (w < 2) {
        float* OwW = Ow + (w & 1) * 32 * 68;
#pragma unroll
        for (int dt = 0; dt < 2; ++dt)
#pragma unroll
            for (int reg = 0; reg < 16; ++reg) {
                const int d = dt * 32 + (reg & 3) + 8 * (reg >> 2) + 4 * h5;
                OwW[l31 * 68 + d] = oacc[dt][reg] * inv;
            }
        asm volatile("s_waitcnt lgkmcnt(0)" ::: "memory");
        const int qq = lane >> 1, half = lane & 1;
        const float* src = &OwW[qq * 68 + half * 32];
        float* dstp = &out[((size_t)b * S_ + q0w + qq) * D_ + h * DH_ + half * 32];
#pragma unroll
        for (int j = 0; j < 8; ++j)
            *(float4*)&dstp[j * 4] = *(const float4*)&src[j * 4];
    }
    __syncthreads();
    if (w >= 2) {
        float* OwW = Ow + (w & 1) * 32 * 68;
#pragma unroll
        for (int dt = 0; dt < 2; ++dt)
#pragma unroll
            for (int reg = 0; reg < 16; ++reg) {
                const int d = dt * 32 + (reg & 3) + 8 * (reg >> 2) + 4 * h5;
                OwW[l31 * 68 + d] = oacc[dt][reg] * inv;
            }
        asm volatile("s_waitcnt lgkmcnt(0)" ::: "memory");
        const int qq = lane >> 1, half = lane & 1;
        const float* src = &OwW[qq * 68 + half * 32];
        float* dstp = &out[((size_t)b * S_ + q0w + qq) * D_ + h * DH_ + half * 32];
#pragma unroll
        for (int j = 0; j < 8; ++j)
            *(float4*)&dstp[j * 4] = *(const float4*)&src[j * 4];
    }
}

// ---------------------------------------------------------------------------
// Global attention phase B: combine chunks (overwrites first-G rows, last).
// ---------------------------------------------------------------------------
__global__ __launch_bounds__(256) void glob_reduce(const float* __restrict__ pout,
                                                   const float* __restrict__ pm,
                                                   const float* __restrict__ pl,
                                                   float* __restrict__ out) {
    const int bh = blockIdx.x;
    const int b = bh / H_, h = bh - b * H_;
    const int t = threadIdx.x;

    __shared__ float wc[G_][NC_];
    __shared__ float wsum[G_];

    const int g = t >> 5, cl = t & 31;
    const float m0 = pm[((size_t)bh * NC_ + cl) * G_ + g];
    const float m1 = pm[((size_t)bh * NC_ + cl + 32) * G_ + g];
    float M = fmaxf(m0, m1);
    M = fmaxf(M, __shfl_xor(M, 1));
    M = fmaxf(M, __shfl_xor(M, 2));
    M = fmaxf(M, __shfl_xor(M, 4));
    M = fmaxf(M, __shfl_xor(M, 8));
    M = fmaxf(M, __shfl_xor(M, 16));
    const float w0 = __expf(m0 - M);
    const float w1 = __expf(m1 - M);
    float S = w0 * pl[((size_t)bh * NC_ + cl) * G_ + g] +
              w1 * pl[((size_t)bh * NC_ + cl + 32) * G_ + g];
    S += __shfl_xor(S, 1);
    S += __shfl_xor(S, 2);
    S += __shfl_xor(S, 4);
    S += __shfl_xor(S, 8);
    S += __shfl_xor(S, 16);
    wc[g][cl] = w0;
    wc[g][cl + 32] = w1;
    if (cl == 0) wsum[g] = S;
    __syncthreads();

#pragma unroll
    for (int pass = 0; pass < 2; ++pass) {
        const int gg = (t >> 6) + pass * 4;
        const int d = t & 63;
        float acc = 0.f;
        for (int c2 = 0; c2 < NC_; ++c2)
            acc += wc[gg][c2] * pout[(((size_t)bh * NC_ + c2) * G_ + gg) * DH_ + d];
        out[((size_t)b * S_ + gg) * D_ + h * DH_ + d] = acc / wsum[gg];
    }
}

// ---------------------------------------------------------------------------
extern "C" void kernel_launch(void* const* d_in, const int* in_sizes, int n_in,
                              void* d_out, int out_size, void* d_ws, size_t ws_size,
                              hipStream_t stream) {
    (void)in_sizes; (void)n_in; (void)out_size; (void)ws_size;

    const float* hs    = (const float*)d_in[0];
    const float* amask = (const float*)d_in[1];
    const float* Wq    = (const float*)d_in[2];
    const float* Wk    = (const float*)d_in[3];
    const float* Wv    = (const float*)d_in[4];
    const float* Wqg   = (const float*)d_in[5];
    const float* Wkg   = (const float*)d_in[6];
    const float* Wvg   = (const float*)d_in[7];
    float* out = (float*)d_out;

    char* p = (char*)d_ws;
    ushort_t* hs_bf = (ushort_t*)p; p += (size_t)B_ * S_ * D_ * 2;
    ushort_t* wt    = (ushort_t*)p; p += (size_t)5 * D_ * D_ * 2;
    const size_t per = (size_t)B_ * H_ * S_ * DH_;
    ushort_t* qb  = (ushort_t*)p; p += per * 2;
    ushort_t* kb  = (ushort_t*)p; p += per * 2;
    ushort_t* vb  = (ushort_t*)p; p += per * 2;
    ushort_t* kgb = (ushort_t*)p; p += per * 2;
    ushort_t* vgb = (ushort_t*)p; p += per * 2;
    float* qg   = (float*)p; p += (size_t)B_ * G_ * D_ * 4;
    float* pout = (float*)p; p += (size_t)B_ * H_ * NC_ * G_ * DH_ * 4;
    float* pm   = (float*)p; p += (size_t)B_ * H_ * NC_ * G_ * 4;
    float* pl   = (float*)p;

    fused_pre<<<6000, 256, 0, stream>>>(hs, Wq, Wk, Wv, Wkg, Wvg, Wqg, hs_bf, wt, qg);
    proj_mfma<<<dim3(B_ * S_ / 128, 5 * D_ / 128), 256, 0, stream>>>(hs_bf, wt, qb, kb, vb, kgb, vgb);
    win_glob<<<NWIN + NC_ * H_ * B_, 256, 0, stream>>>(qb, kb, vb, amask, out,
                                                       qg, kgb, vgb, pout, pm, pl);
    glob_reduce<<<B_ * H_, 256, 0, stream>>>(pout, pm, pl, out);
}